// Round 25
// baseline (41.727 us; speedup 1.0000x reference)
//
#include <hip/hip_runtime.h>

// Problem constants: B=8, S=1024, E=128, H=32, DK=4.
constexpr int kS = 1024;
constexpr int NM = 126;  // monomials of degree <=5 in 4 vars: C(9,4)

typedef __fp16 fp16x2 __attribute__((ext_vector_type(2)));
typedef _Float16 half4v __attribute__((ext_vector_type(4)));
typedef _Float16 half8v __attribute__((ext_vector_type(8)));
typedef float float4v __attribute__((ext_vector_type(4)));

// ---------------------------------------------------------------------------
// Feature-map attention (verified R14-R24): P[q,k] = e^{q.k/2}, deg-5
// Chebyshev basis (126 monomials).
//   M[a][c]  = sum_k m_k[a]*vv_k[c]   (vv = [z,1]; col 4 = denominator)
//   num[q][c] = sum_a m_q[a] * (w_a M[a][c]);  out = num[0..3]/num[4].
// R25: featC -> MFMA. A = per-q monomial rows (LDS, uint4-aligned), B = f16
// (w*M) fragment table (R16-verified layout, only 4KB here), MFMA slot
// pairing identical to featM/combine. 128 q/block, grid 2048, 39KB LDS ->
// 4 blocks/CU. Epilogue gathers num cols + den via shfl (m89 C/D mapping).
// A k-slots 126-135 zeroed per row (NaN*0 propagates through MFMA).
// ---------------------------------------------------------------------------

__device__ __forceinline__ float wcoef(int a0, int a1, int a2, int a3) {
  const float b[6] = {1.0031455f, 1.0010453f, 0.4860342f,
                      0.1641117f, 0.0507286f, 0.0097257f};
  const float f[6] = {1.f, 1.f, 2.f, 6.f, 24.f, 120.f};
  const float p2[6] = {1.f, 2.f, 4.f, 8.f, 16.f, 32.f};
  int n = a0 + a1 + a2 + a3;
  return b[n] * f[n] / (p2[n] * f[a0] * f[a1] * f[a2] * f[a3]);
}

// Canonical graded enumeration of the 126 deg<=5 monomials; shared by all
// kernels so slot s <-> monomial s is consistent (MFMA A/B pairing).
template <class F>
__device__ __forceinline__ void for_each_mono(float z0, float z1, float z2,
                                              float z3, F&& f) {
  int idx = 0;
  float p0 = 1.f;
#pragma unroll
  for (int a0 = 0; a0 <= 5; ++a0) {
    float p1 = p0;
#pragma unroll
    for (int a1 = 0; a1 <= 5 - a0; ++a1) {
      float p2 = p1;
#pragma unroll
      for (int a2 = 0; a2 <= 5 - a0 - a1; ++a2) {
        float p3 = p2;
#pragma unroll
        for (int a3 = 0; a3 <= 5 - a0 - a1 - a2; ++a3) {
          f(idx, p3, a0, a1, a2, a3);
          ++idx;
          p3 *= z3;
        }
        p2 *= z2;
      }
      p1 *= z1;
    }
    p0 *= z0;
  }
}

// ---------------------------------------------------------------------------
// K1: quantum encoder (analytic collapse, verified R1-R24) + W pack fused.
// ---------------------------------------------------------------------------
__global__ __launch_bounds__(256) void qenc_kernel(
    const float4* __restrict__ x4, const float* __restrict__ qp,
    uint2* __restrict__ h16u, const float* __restrict__ W,
    _Float16* __restrict__ wtb) {
  int idx = blockIdx.x * 256 + threadIdx.x;
  if (blockIdx.x < 64) {
    int i = idx;  // 0..16383
    int col = i >> 7, e = i & 127;
    wtb[((e >> 3) << 10) + (col << 3) + (e & 7)] = (_Float16)W[i];
  }
  float4 a = x4[idx];
  float c0 = cosf(a.x + qp[0]);
  float c1 = cosf(a.y + qp[1]);
  float c2 = cosf(a.z + qp[2]);
  float c3 = cosf(a.w + qp[3]);
  float z1 = c0 * c1;
  float z2 = z1 * c2;
  float z3 = z2 * c3;
  float z0 = c1 * c2 * c3;
  union { half4v h; uint2 u; } z;
  z.h.x = (_Float16)z0;
  z.h.y = (_Float16)z1;
  z.h.z = (_Float16)z2;
  z.h.w = (_Float16)z3;
  int b = idx >> 15;
  int s = (idx >> 5) & (kS - 1);
  int head = idx & 31;
  int bh = b * 32 + head;
  h16u[(bh << 10) + s] = z.u;
}

// ---------------------------------------------------------------------------
// K2a (R21/R22-verbatim, verified): M[bh][half][row][c] via MFMA phase 2.
// ---------------------------------------------------------------------------
__global__ __launch_bounds__(256) void featM_kernel(
    const _Float16* __restrict__ h16, float* __restrict__ Mpart) {
  __shared__ ushort sm[128][136];  // 272B rows = 17 uint4, b128-aligned
  __shared__ ushort vvb[2048];     // [kb(16)][col(16)][j(8)] f16
  const int bh = blockIdx.x >> 1;
  const int half = blockIdx.x & 1;
  const int t = threadIdx.x;
  const bool hiH = t >= 128;
  const int tok = t & 127;
  const uint2* __restrict__ hb = (const uint2*)(h16) + (bh << 10) + (half << 9);

  // One-time init: sm pad rows (126,127) zero; vvb col4 = 1.0, cols 5-15 = 0.
  for (int i = t; i < 2 * 136; i += 256) sm[126 + i / 136][i % 136] = 0;
  for (int i = t; i < 2048; i += 256)
    vvb[i] = (((i >> 3) & 15) == 4) ? (ushort)0x3C00u : (ushort)0u;

  const int lane = t & 63;
  const int w = t >> 6;
  const int c = lane & 15, g = lane >> 4;
  float4v acc[2] = {};

  for (int ch = 0; ch < 4; ++ch) {
    __syncthreads();  // covers init on ch=0; phase2->phase1 on later chunks
    {
      union { uint2 u; half4v h; ushort4 us; } uz;
      uz.u = hb[(ch << 7) + tok];
      float z0 = (float)uz.h.x, z1 = (float)uz.h.y;
      float z2 = (float)uz.h.z, z3 = (float)uz.h.w;
      if (!hiH) {
        int base = ((tok >> 3) << 7) + (tok & 7);
        vvb[base + 0] = uz.us.x;   // col 0
        vvb[base + 8] = uz.us.y;   // col 1
        vvb[base + 16] = uz.us.z;  // col 2
        vvb[base + 24] = uz.us.w;  // col 3
      }
      for_each_mono(z0, z1, z2, z3,
                    [&](int mi, float m, int, int, int, int) {
                      if (hiH ? (mi >= 63) : (mi < 63)) {
                        union { _Float16 h; ushort u; } cv;
                        cv.h = (_Float16)m;
                        sm[mi][tok] = cv.u;
                      }
                    });
    }
    __syncthreads();
    {
      const uint4* __restrict__ vvb4 = (const uint4*)vvb;
      union U4H { uint4 u; half8v h; };
#pragma unroll
      for (int ks = 0; ks < 4; ++ks) {
        U4H ub;
        ub.u = vvb4[(((ks << 2) + g) << 4) + c];
#pragma unroll
        for (int tl = 0; tl < 2; ++tl) {
          const uint4* arow4 = (const uint4*)&sm[(w << 5) + (tl << 4) + c][0];
          U4H ua;
          ua.u = arow4[(ks << 2) + g];
          acc[tl] = __builtin_amdgcn_mfma_f32_16x16x32_f16(ua.h, ub.h,
                                                           acc[tl], 0, 0, 0);
        }
      }
    }
  }

  if (c < 5) {
    float* mp = Mpart + ((bh << 1) + half) * NM * 5;
#pragma unroll
    for (int tl = 0; tl < 2; ++tl) {
#pragma unroll
      for (int reg = 0; reg < 4; ++reg) {
        int row = (w << 5) + (tl << 4) + (g << 2) + reg;
        if (row < NM) mp[row * 5 + c] = acc[tl][reg];
      }
    }
  }
}

// ---------------------------------------------------------------------------
// K2b v8 (MFMA): num[128 q][5] = m_q[128x128] @ (w*M)[128x5].
// Block = (bh, q-chunk 128), grid 2048.
//   mwb: f16 B-table [k>>3][col16][k&7] (R16-verified build; 4KB; cols 5-15
//        and k>=126 zeroed; col 4 = denominator).
//   sm:  per-q monomial rows, uint4-aligned; t<128 writes monos 0-62 of row
//        t, t>=128 writes 63-125 + zero tail 126-135 of row t-128.
//   MFMA: 2 row-tiles/wave x 4 k-steps, featM/combine slot pairing.
//   Epilogue: C/D row=(g<<2)+reg col=c; shfl-gather n1..n3,den; c==0 stores.
// ---------------------------------------------------------------------------
__global__ __launch_bounds__(256) void featC_kernel(
    const _Float16* __restrict__ h16, const float* __restrict__ Mpart,
    uint2* __restrict__ o16u2) {
  __shared__ uint4 sm4[128][17];   // rows of 136 u16, b128-aligned
  __shared__ ushort mwb[2048];     // [k>>3][col(16)][k&7] f16
  const int bh = blockIdx.x >> 3;
  const int qc = blockIdx.x & 7;
  const int t = threadIdx.x;

  // zero the B table (as uints)
  {
    uint* mw32 = (uint*)mwb;
    mw32[t] = 0u;
    mw32[t + 256] = 0u;
    mw32[t + 512] = 0u;
    mw32[t + 768] = 0u;
  }
  __syncthreads();

  // fill B: mwb[k=t][c] = f16(w_t * (Mpart_h0 + Mpart_h1)), c = 0..4
  if (t < NM) {
    float w = 0.f;
    for_each_mono(1.f, 1.f, 1.f, 1.f,
                  [&](int mi, float, int a0, int a1, int a2, int a3) {
                    if (mi == t) w = wcoef(a0, a1, a2, a3);
                  });
    const float* p0 = Mpart + ((bh << 1) * NM + t) * 5;
    const float* p1 = p0 + NM * 5;
    int base = ((t >> 3) << 7) + (t & 7);
#pragma unroll
    for (int c = 0; c < 5; ++c) {
      union { _Float16 h; ushort u; } cv;
      cv.h = (_Float16)(w * (p0[c] + p1[c]));
      mwb[base + (c << 3)] = cv.u;
    }
  }

  // generate monomial rows: q = qc*128 + row, row = t&127
  {
    const int row = t & 127;
    const bool hiH = t >= 128;
    union { uint2 u; half4v h; } uz;
    uz.u = ((const uint2*)h16)[(bh << 10) + (qc << 7) + row];
    float z0 = (float)uz.h.x, z1 = (float)uz.h.y;
    float z2 = (float)uz.h.z, z3 = (float)uz.h.w;
    ushort* srow = (ushort*)&sm4[row][0];
    for_each_mono(z0, z1, z2, z3,
                  [&](int mi, float m, int, int, int, int) {
                    if (hiH ? (mi >= 63) : (mi < 63)) {
                      union { _Float16 h; ushort u; } cv;
                      cv.h = (_Float16)m;
                      srow[mi] = cv.u;
                    }
                  });
    if (hiH) {  // zero tail k=126..135 (B is zero there, but NaN*0 = NaN)
      uint* srow32 = (uint*)srow;
      srow32[63] = 0u; srow32[64] = 0u; srow32[65] = 0u;
      srow32[66] = 0u; srow32[67] = 0u;
    }
  }
  __syncthreads();

  // MFMA: 2 row-tiles per wave x 4 k-steps
  const int lane = t & 63;
  const int w_ = t >> 6;
  const int c = lane & 15, g = lane >> 4;
  const uint4* __restrict__ mwb4 = (const uint4*)mwb;
  union U4H { uint4 u; half8v h; };
  float4v acc[2] = {};
#pragma unroll
  for (int ks = 0; ks < 4; ++ks) {
    U4H ub;
    ub.u = mwb4[(((ks << 2) + g) << 4) + c];
#pragma unroll
    for (int tl = 0; tl < 2; ++tl) {
      U4H ua;
      ua.u = sm4[(w_ << 5) + (tl << 4) + c][(ks << 2) + g];
      acc[tl] = __builtin_amdgcn_mfma_f32_16x16x32_f16(ua.h, ub.h,
                                                       acc[tl], 0, 0, 0);
    }
  }

  // epilogue: D[row][col]: col=lane&15, row=(lane>>4)*4+reg (m89-verified).
  const int b_ = bh >> 5, head = bh & 31;
  const int gbase = lane & 48;
#pragma unroll
  for (int tl = 0; tl < 2; ++tl) {
#pragma unroll
    for (int reg = 0; reg < 4; ++reg) {
      float v = acc[tl][reg];
      float n1 = __shfl(v, gbase | 1);
      float n2 = __shfl(v, gbase | 2);
      float n3 = __shfl(v, gbase | 3);
      float den = __shfl(v, gbase | 4);
      if (c == 0) {
        float inv = 1.0f / den;
        union { fp16x2 p[2]; uint2 u; } res;
        res.p[0] = __builtin_amdgcn_cvt_pkrtz(v * inv, n1 * inv);
        res.p[1] = __builtin_amdgcn_cvt_pkrtz(n2 * inv, n3 * inv);
        int q = (qc << 7) + (w_ << 5) + (tl << 4) + (g << 2) + reg;
        o16u2[(((b_ << 10) + q) << 5) + head] = res.u;
      }
    }
  }
}

// ---------------------------------------------------------------------------
// K3: combine GEMM out[8192][128] = o16 @ W^T via mfma_f32_16x16x32_f16.
// (verified R6-R24: ~3 us)
// ---------------------------------------------------------------------------
__global__ __launch_bounds__(256) void combine_kernel(
    const _Float16* __restrict__ o16, const _Float16* __restrict__ wtb,
    float* __restrict__ out) {
  const int lane = threadIdx.x & 63;
  const int wv = threadIdx.x >> 6;
  const int job = blockIdx.x * 4 + wv;  // 0..4095
  const int rt = job >> 3, ct = job & 7;
  const int c = lane & 15, g = lane >> 4;
  const uint4* a4 = (const uint4*)o16;
  const uint4* b4 = (const uint4*)wtb;
  const int arow = (rt << 4) + c;
  union U4H { uint4 u; half8v h; };
  float4v acc = {};
#pragma unroll
  for (int t = 0; t < 4; ++t) {
    U4H ua, ub;
    ua.u = a4[(arow << 4) + (t << 2) + g];
    ub.u = b4[(((t << 2) + g) << 7) + (ct << 4) + c];
    acc = __builtin_amdgcn_mfma_f32_16x16x32_f16(ua.h, ub.h, acc, 0, 0, 0);
  }
  const int orow = (rt << 4) + (g << 2);
  const int ocol = (ct << 4) + c;
#pragma unroll
  for (int reg = 0; reg < 4; ++reg)
    out[(orow + reg) * 128 + ocol] = acc[reg];
}

extern "C" void kernel_launch(void* const* d_in, const int* in_sizes, int n_in,
                              void* d_out, int out_size, void* d_ws,
                              size_t ws_size, hipStream_t stream) {
  const float* x = (const float*)d_in[0];   // [8,1024,128] f32
  const float* qp = (const float*)d_in[1];  // [1,4] f32
  const float* W = (const float*)d_in[2];   // [128,128] f32
  float* out = (float*)d_out;               // [8,1024,128] f32

  char* ws = (char*)d_ws;
  _Float16* h16 = (_Float16*)ws;                 // [256][1024][4] f16 = 2 MB
  float* Mpart = (float*)(ws + (2 << 20));       // [256][2][126][5] f32 ~1.3MB
  _Float16* o16 = (_Float16*)(ws + (6 << 20));   // [8192][128] f16 = 2 MB
  _Float16* wtb = (_Float16*)(ws + (8 << 20));   // [16][128][8] f16 = 32 KB

  qenc_kernel<<<1024, 256, 0, stream>>>((const float4*)x, qp, (uint2*)h16, W,
                                        wtb);
  featM_kernel<<<512, 256, 0, stream>>>(h16, Mpart);
  featC_kernel<<<2048, 256, 0, stream>>>(h16, Mpart, (uint2*)o16);
  combine_kernel<<<1024, 256, 0, stream>>>(o16, wtb, out);
}